// Round 6
// baseline (1354.373 us; speedup 1.0000x reference)
//
#include <hip/hip_runtime.h>
#include <math.h>
#include <stdint.h>

#define VOL 110592   // 48*48*48
#define CINP 64      // input channels
#define PCH 64       // proj channels

typedef short short8 __attribute__((ext_vector_type(8)));
typedef float floatx4 __attribute__((ext_vector_type(4)));
typedef _Float16 h8 __attribute__((ext_vector_type(8)));
typedef _Float16 h2v __attribute__((ext_vector_type(2)));

__device__ __forceinline__ ushort f2bf(float f) {
    union { float f; uint32_t u; } v; v.f = f;
    uint32_t r = v.u + 0x7FFFu + ((v.u >> 16) & 1u);   // RNE
    return (ushort)(r >> 16);
}

__device__ __forceinline__ float hdot2(h2v a, h2v b, float c) {
#if __has_builtin(__builtin_amdgcn_fdot2)
    return __builtin_amdgcn_fdot2(a, b, c, false);
#else
    return fmaf((float)a[0], (float)b[0], fmaf((float)a[1], (float)b[1], c));
#endif
}

// ---------------------------------------------------------------------------
// 1x1x1 conv (64x64 matvec) + bias + channel L2-normalize. fp16 voxel-major
// output (post-norm values in [-1,1] -> fp16-safe).
__global__ __launch_bounds__(256) void proj_l2norm_kernel(
    const float* __restrict__ x,   // [64][VOL]
    const float* __restrict__ w,   // [64][64]
    const float* __restrict__ b,   // [64]
    _Float16* __restrict__ out)    // [VOL][64]
{
    const int v = blockIdx.x * 256 + threadIdx.x;
    float xr[CINP];
    for (int ci = 0; ci < CINP; ci++)
        xr[ci] = x[(size_t)ci * VOL + v];

    float acc[PCH];
    for (int c = 0; c < PCH; c++) {
        float a = b[c];
        #pragma unroll
        for (int ci = 0; ci < CINP; ci++)
            a = fmaf(w[c * CINP + ci], xr[ci], a);
        acc[c] = a;
    }
    float s = 0.f;
    #pragma unroll
    for (int c = 0; c < PCH; c++) s += acc[c] * acc[c];
    const float inv = 1.0f / fmaxf(sqrtf(s), 1e-12f);
    #pragma unroll
    for (int c = 0; c < PCH; c++)
        out[(size_t)v * PCH + c] = (_Float16)(acc[c] * inv);
}

// ---------------------------------------------------------------------------
// Fused correlation (343 offsets, edge-clamped) + softmax expected-offset.
// This round: per dy-row, issue all 7 dx tv-loads back-to-back (MLP=7)
// before the 7 compute bodies -> one latency exposure per 7 taps instead
// of 7. Compute order (and numerics) unchanged.
__global__ __launch_bounds__(256) void corr_fused_kernel(
    const _Float16* __restrict__ sp,   // [VOL][64]
    const _Float16* __restrict__ tp,   // [VOL][64]
    ushort* __restrict__ featT)        // [VOL][352] bf16
{
    const int t  = threadIdx.x;
    const int c8 = t & 7;
    const int vg = t >> 3;
    const int v  = blockIdx.x * 32 + vg;
    const int x = v % 48, y = (v / 48) % 48, z = v / 2304;

    __shared__ __align__(16) ushort lds[32 * 360];   // 23 KB

    const h8 s = *(const h8*)(sp + (size_t)v * PCH + c8 * 8);

    float ssum = 0.f, e0 = 0.f, e1 = 0.f, e2 = 0.f;
    int k = 0;
    for (int dz = -3; dz <= 3; dz++) {
        const int zb = min(max(z + dz, 0), 47) * 2304;
        const float fdz = (float)dz;
        for (int dy = -3; dy <= 3; dy++) {
            const int rb = zb + min(max(y + dy, 0), 47) * 48;
            const float fdy = (float)dy;
            // issue all 7 loads first (static-indexed regs, stays in VGPRs)
            h8 tv[7];
            #pragma unroll
            for (int dxi = 0; dxi < 7; dxi++) {
                const int xc = min(max(x + dxi - 3, 0), 47);
                tv[dxi] = *(const h8*)(tp + (size_t)(rb + xc) * PCH + c8 * 8);
            }
            #pragma unroll
            for (int dxi = 0; dxi < 7; dxi++) {
                const h8 tvv = tv[dxi];
                float d0 = hdot2((h2v){s[0], s[1]}, (h2v){tvv[0], tvv[1]}, 0.f);
                d0 = hdot2((h2v){s[2], s[3]}, (h2v){tvv[2], tvv[3]}, d0);
                float d1 = hdot2((h2v){s[4], s[5]}, (h2v){tvv[4], tvv[5]}, 0.f);
                d1 = hdot2((h2v){s[6], s[7]}, (h2v){tvv[6], tvv[7]}, d1);
                float dot = d0 + d1;
                dot += __shfl_xor(dot, 1);
                dot += __shfl_xor(dot, 2);
                dot += __shfl_xor(dot, 4);
                if (c8 == 0) lds[vg * 360 + k + dxi] = f2bf(dot);
                const float e = __expf(dot);   // |dot|<=1: no max-subtraction
                ssum += e;
                e0 += e * fdz;
                e1 += e * fdy;
                e2 += e * (float)(dxi - 3);
            }
            k += 7;
        }
    }

    if (c8 == 0) {
        const float inv = 1.f / ssum;
        lds[vg * 360 + 343] = f2bf(e0 * inv);
        lds[vg * 360 + 344] = f2bf(e1 * inv);
        lds[vg * 360 + 345] = f2bf(e2 * inv);
        #pragma unroll
        for (int j = 346; j < 352; j++) lds[vg * 360 + j] = 0;
    }
    __syncthreads();

    ushort* ob = featT + (size_t)blockIdx.x * 32 * 352;
    #pragma unroll
    for (int j = 0; j < 6; j++) {
        const int idx = t + j * 256;
        if (idx < 1408) {
            const int row = idx / 44, col = (idx % 44) * 8;
            *(int4*)(ob + (size_t)row * 352 + col) = *(const int4*)(&lds[row * 360 + col]);
        }
    }
}

// ---------------------------------------------------------------------------
// Weight pre-transpose: w[128][CIN][27] fp32 -> wT[27][128][CPAD] bf16 (pad 0).
// Block 0 also zero-fills the 16B global pad used by conv staging.
template<int CIN, int CPAD>
__global__ __launch_bounds__(256) void wprep_kernel(
    const float* __restrict__ w, ushort* __restrict__ wTo, float* __restrict__ zp)
{
    if (blockIdx.x == 0 && threadIdx.x < 4) zp[threadIdx.x] = 0.f;
    const int oc = blockIdx.x;
    for (int idx = threadIdx.x; idx < CPAD * 27; idx += 256) {
        const int icp = idx / 27, tap = idx - icp * 27;
        float val = 0.f;
        if (icp < CIN) val = w[((size_t)oc * CIN + icp) * 27 + tap];
        wTo[((size_t)tap * 128 + oc) * CPAD + icp] = f2bf(val);
    }
}

// ---------------------------------------------------------------------------
// Implicit-GEMM 3x3x3 conv via bf16 MFMA (zero padding).
// Round-2 structure + XCD-chunked swizzle (round-5 win: FETCH 250->107MB).
// This round: FULL tap-loop unroll — all 27 tap bodies visible to the
// scheduler so ds_reads / A-loads of later taps hoist above earlier taps'
// MFMAs (counted lgkmcnt/vmcnt instead of one exposed latency chain per
// tap-pair). launch_bounds(256,4) caps registers; compiler throttles
// hoisting rather than spilling.
// Block: 128 voxels (2z x 4y x 16x) x 128 oc, 4 waves.
template<int CPAD>
__global__ __launch_bounds__(256, 4) void conv3_mfma_kernel(
    const ushort* __restrict__ xT,   // [VOL][CPAD] bf16
    const ushort* __restrict__ wT,   // [27][128][CPAD] bf16
    const float* __restrict__ bias,  // [128]
    const ushort* __restrict__ zpad, // 16B of zeros
    float* __restrict__ out)         // [128][VOL] fp32
{
    // XCD-chunked swizzle: grid 864, 8 XCDs -> chunk of 108 contiguous
    // logical blocks per XCD. Bijective since 864 % 8 == 0.
    const int blk = (blockIdx.x % 8) * 108 + (blockIdx.x / 8);
    const int tx = blk % 3, ty = (blk / 3) % 12, tz = blk / 36;
    const int x0 = tx * 16, y0 = ty * 4, z0 = tz * 2;
    const int t = threadIdx.x;
    const int wave = t >> 6;
    const int lane = t & 63;
    const int l = lane & 15;
    const int q = lane >> 4;
    const int ocw = (wave & 1) * 64;
    const int mzw = wave >> 1;

    __shared__ __align__(16) ushort win[432 * 32];   // 27 KB, linear

    // per-lane staging byte offsets into xT (chunk 0), -1 = halo/OOB -> zpad.
    int off[7];
    #pragma unroll
    for (int it = 0; it < 7; it++) {
        const int c = wave + it * 4;
        off[it] = -1;
        if (c < 27) {
            const int i = c * 64 + lane;
            const int p = i >> 2, g = i & 3;
            const int wz = p / 108, pr = p - wz * 108;
            const int wy = pr / 18, wx = pr - wy * 18;
            const int gz = z0 + wz - 1, gy = y0 + wy - 1, gx = x0 + wx - 1;
            if ((unsigned)gx < 48u && (unsigned)gy < 48u && (unsigned)gz < 48u)
                off[it] = ((gz * 2304 + gy * 48 + gx) * CPAD + g * 8) * 2;
        }
    }

    floatx4 acc[4][4];   // acc[oc-subtile j][voxel-subtile mt]
    #pragma unroll
    for (int i = 0; i < 4; i++)
        #pragma unroll
        for (int j = 0; j < 4; j++)
            acc[i][j] = (floatx4){0.f, 0.f, 0.f, 0.f};

    const ushort* wbase = wT + (size_t)(ocw + l) * CPAD + q * 8;
    const int ldsbase = (mzw * 108 + l) * 32 + q * 8;

    const int NCH = CPAD / 32;
    #pragma unroll 1
    for (int ck = 0; ck < NCH; ck++) {
        if (ck) __syncthreads();           // all readers of win done

        // stage chunk ck: 27 x global_load_lds_dwordx4 (linear LDS dest)
        const char* xck = (const char*)xT + (size_t)ck * 64;
        #pragma unroll
        for (int it = 0; it < 7; it++) {
            const int c = wave + it * 4;
            if (c < 27) {
                const ushort* gp = (off[it] >= 0)
                    ? (const ushort*)(xck + off[it])
                    : zpad;
                __builtin_amdgcn_global_load_lds(
                    (const __attribute__((address_space(1))) uint32_t*)gp,
                    (__attribute__((address_space(3))) uint32_t*)(win + c * 512 + lane * 8),
                    16, 0, 0);
            }
        }

        // prologue: tap 0 weights into A0 (L2-resident; drained by barrier)
        const ushort* wck = wbase + ck * 32;
        short8 A0[4], A1[4];
        A0[0] = *(const short8*)(wck);
        A0[1] = *(const short8*)(wck + 16 * CPAD);
        A0[2] = *(const short8*)(wck + 32 * CPAD);
        A0[3] = *(const short8*)(wck + 48 * CPAD);

        __syncthreads();                   // vmcnt(0)+lgkmcnt(0) drain + barrier

        // body(TP): prefetch tap TP+1 into AL, compute tap TP from AU.
#define CONV_BODY(TP, AU, AL)                                              \
        {                                                                  \
            const int tpn_ = (TP) + 1;                                     \
            if (tpn_ < 27) {                                               \
                const ushort* wp_ = wck + (size_t)tpn_ * (128 * CPAD);     \
                AL[0] = *(const short8*)(wp_);                             \
                AL[1] = *(const short8*)(wp_ + 16 * CPAD);                 \
                AL[2] = *(const short8*)(wp_ + 32 * CPAD);                 \
                AL[3] = *(const short8*)(wp_ + 48 * CPAD);                 \
            }                                                              \
            const int dz_ = (TP) / 9;                                      \
            const int dy_ = ((TP) / 3) % 3;                                \
            const int dx_ = (TP) % 3;                                      \
            const int pb_ = ldsbase + (dz_ * 108 + dy_ * 18 + dx_) * 32;   \
            const short8 b0_ = *(const short8*)(&win[pb_ +    0]);         \
            const short8 b1_ = *(const short8*)(&win[pb_ +  576]);         \
            const short8 b2_ = *(const short8*)(&win[pb_ + 1152]);         \
            const short8 b3_ = *(const short8*)(&win[pb_ + 1728]);         \
            acc[0][0] = __builtin_amdgcn_mfma_f32_16x16x32_bf16(AU[0], b0_, acc[0][0], 0, 0, 0); \
            acc[1][0] = __builtin_amdgcn_mfma_f32_16x16x32_bf16(AU[1], b0_, acc[1][0], 0, 0, 0); \
            acc[2][0] = __builtin_amdgcn_mfma_f32_16x16x32_bf16(AU[2], b0_, acc[2][0], 0, 0, 0); \
            acc[3][0] = __builtin_amdgcn_mfma_f32_16x16x32_bf16(AU[3], b0_, acc[3][0], 0, 0, 0); \
            acc[0][1] = __builtin_amdgcn_mfma_f32_16x16x32_bf16(AU[0], b1_, acc[0][1], 0, 0, 0); \
            acc[1][1] = __builtin_amdgcn_mfma_f32_16x16x32_bf16(AU[1], b1_, acc[1][1], 0, 0, 0); \
            acc[2][1] = __builtin_amdgcn_mfma_f32_16x16x32_bf16(AU[2], b1_, acc[2][1], 0, 0, 0); \
            acc[3][1] = __builtin_amdgcn_mfma_f32_16x16x32_bf16(AU[3], b1_, acc[3][1], 0, 0, 0); \
            acc[0][2] = __builtin_amdgcn_mfma_f32_16x16x32_bf16(AU[0], b2_, acc[0][2], 0, 0, 0); \
            acc[1][2] = __builtin_amdgcn_mfma_f32_16x16x32_bf16(AU[1], b2_, acc[1][2], 0, 0, 0); \
            acc[2][2] = __builtin_amdgcn_mfma_f32_16x16x32_bf16(AU[2], b2_, acc[2][2], 0, 0, 0); \
            acc[3][2] = __builtin_amdgcn_mfma_f32_16x16x32_bf16(AU[3], b2_, acc[3][2], 0, 0, 0); \
            acc[0][3] = __builtin_amdgcn_mfma_f32_16x16x32_bf16(AU[0], b3_, acc[0][3], 0, 0, 0); \
            acc[1][3] = __builtin_amdgcn_mfma_f32_16x16x32_bf16(AU[1], b3_, acc[1][3], 0, 0, 0); \
            acc[2][3] = __builtin_amdgcn_mfma_f32_16x16x32_bf16(AU[2], b3_, acc[2][3], 0, 0, 0); \
            acc[3][3] = __builtin_amdgcn_mfma_f32_16x16x32_bf16(AU[3], b3_, acc[3][3], 0, 0, 0); \
        }

        // FULL unroll: all 27 bodies visible to the scheduler.
        #pragma unroll
        for (int tg = 0; tg < 13; tg++) {
            const int tp = tg * 2;
            CONV_BODY(tp, A0, A1);
            CONV_BODY(tp + 1, A1, A0);
        }
        CONV_BODY(26, A0, A1);
#undef CONV_BODY
    }

    #pragma unroll
    for (int nt = 0; nt < 4; nt++) {
        const int ocb = ocw + nt * 16 + q * 4;
        const float4 bv = *(const float4*)(bias + ocb);
        #pragma unroll
        for (int mt = 0; mt < 4; mt++) {
            const int v = (z0 + mzw) * 2304 + (y0 + mt) * 48 + x0 + l;
            out[(size_t)(ocb + 0) * VOL + v] = acc[nt][mt][0] + bv.x;
            out[(size_t)(ocb + 1) * VOL + v] = acc[nt][mt][1] + bv.y;
            out[(size_t)(ocb + 2) * VOL + v] = acc[nt][mt][2] + bv.z;
            out[(size_t)(ocb + 3) * VOL + v] = acc[nt][mt][3] + bv.w;
        }
    }
}

// ---------------------------------------------------------------------------
// Two-phase per-channel stats. Phase 1: grid (128, 8) partial sums.
__global__ __launch_bounds__(256) void chan_stats_part_kernel(
    const float* __restrict__ x, float* __restrict__ pstats /* [128][8][2] */)
{
    const int c = blockIdx.x, g = blockIdx.y;
    const float4* p = (const float4*)(x + (size_t)c * VOL) + g * 3456;
    float s = 0.f, s2 = 0.f;
    #pragma unroll
    for (int j = 0; j < 14; j++) {
        const int i = threadIdx.x + j * 256;
        if (i < 3456) {
            const float4 v = p[i];
            s += v.x + v.y + v.z + v.w;
            s2 = fmaf(v.x, v.x, fmaf(v.y, v.y, fmaf(v.z, v.z, fmaf(v.w, v.w, s2))));
        }
    }
    s  += __shfl_down(s, 32);  s  += __shfl_down(s, 16);
    s  += __shfl_down(s, 8);   s  += __shfl_down(s, 4);
    s  += __shfl_down(s, 2);   s  += __shfl_down(s, 1);
    s2 += __shfl_down(s2, 32); s2 += __shfl_down(s2, 16);
    s2 += __shfl_down(s2, 8);  s2 += __shfl_down(s2, 4);
    s2 += __shfl_down(s2, 2);  s2 += __shfl_down(s2, 1);
    __shared__ float rs[4], rs2[4];
    if ((threadIdx.x & 63) == 0) {
        rs[threadIdx.x >> 6] = s;
        rs2[threadIdx.x >> 6] = s2;
    }
    __syncthreads();
    if (threadIdx.x == 0) {
        pstats[(c * 8 + g) * 2]     = rs[0] + rs[1] + rs[2] + rs[3];
        pstats[(c * 8 + g) * 2 + 1] = rs2[0] + rs2[1] + rs2[2] + rs2[3];
    }
}

// Phase 2: 1 block, 128 threads -> mean/rstd.
__global__ __launch_bounds__(128) void chan_stats_fin_kernel(
    const float* __restrict__ pstats, float* __restrict__ stats /* [128][2] */)
{
    const int c = threadIdx.x;
    float s = 0.f, s2 = 0.f;
    #pragma unroll
    for (int g = 0; g < 8; g++) {
        s  += pstats[(c * 8 + g) * 2];
        s2 += pstats[(c * 8 + g) * 2 + 1];
    }
    const float mean = s / (float)VOL;
    const float var  = s2 / (float)VOL - mean * mean;
    stats[c * 2]     = mean;
    stats[c * 2 + 1] = rsqrtf(var + 1e-5f);
}

__device__ __forceinline__ float gelu_exact(float h)
{
    return 0.5f * h * (1.f + erff(h * 0.70710678118654752f));
}

// Elementwise instance-norm apply + exact GELU (final output, fp32).
__global__ __launch_bounds__(256) void norm_gelu_kernel(
    const float* __restrict__ x, const float* __restrict__ stats,
    float* __restrict__ out)
{
    const size_t i = (size_t)blockIdx.x * 256 + threadIdx.x;  // float4 index
    const int c = (int)(i / (VOL / 4));
    const float mean = stats[c * 2], rstd = stats[c * 2 + 1];
    const float4 xv = ((const float4*)x)[i];
    float4 o;
    o.x = gelu_exact((xv.x - mean) * rstd);
    o.y = gelu_exact((xv.y - mean) * rstd);
    o.z = gelu_exact((xv.z - mean) * rstd);
    o.w = gelu_exact((xv.w - mean) * rstd);
    ((float4*)out)[i] = o;
}

// ---------------------------------------------------------------------------
// Fused: instance-norm apply + GELU + transpose [128][VOL] fp32 -> [VOL][128]
// bf16 (32x32 LDS tiles).
__global__ __launch_bounds__(256) void norm_gelu_transpose_kernel(
    const float* __restrict__ x, const float* __restrict__ stats,
    ushort* __restrict__ outT)
{
    __shared__ float tile[32][33];
    const int v0 = blockIdx.x * 32;
    const int c0 = blockIdx.y * 32;
    const int t = threadIdx.x;
    const int vl = t & 31, cl = t >> 5;
    #pragma unroll
    for (int i = 0; i < 4; i++) {
        const int c = c0 + cl + i * 8;
        const float mean = stats[c * 2], rstd = stats[c * 2 + 1];
        const float val = x[(size_t)c * VOL + v0 + vl];
        tile[cl + i * 8][vl] = gelu_exact((val - mean) * rstd);
    }
    __syncthreads();
    const int vw = t >> 3, cg = t & 7;
    ushort4 o;
    o.x = f2bf(tile[cg * 4 + 0][vw]);
    o.y = f2bf(tile[cg * 4 + 1][vw]);
    o.z = f2bf(tile[cg * 4 + 2][vw]);
    o.w = f2bf(tile[cg * 4 + 3][vw]);
    *(ushort4*)(outT + (size_t)(v0 + vw) * 128 + c0 + cg * 4) = o;
}

// ---------------------------------------------------------------------------
extern "C" void kernel_launch(void* const* d_in, const int* in_sizes, int n_in,
                              void* d_out, int out_size, void* d_ws, size_t ws_size,
                              hipStream_t stream)
{
    const float* src = (const float*)d_in[0];
    const float* tgt = (const float*)d_in[1];
    const float* psw = (const float*)d_in[2];
    const float* psb = (const float*)d_in[3];
    const float* ptw = (const float*)d_in[4];
    const float* ptb = (const float*)d_in[5];
    const float* e1w = (const float*)d_in[6];
    const float* e1b = (const float*)d_in[7];
    const float* e2w = (const float*)d_in[8];
    const float* e2b = (const float*)d_in[9];

    float* ws = (float*)d_ws;
    // Workspace (float-unit offsets; V = VOL):
    //   sp/tp fp16 [0,64V)        dead after corr -> h1 (fp32) reuses [0,128V)
    //   featT bf16 [128V,304V)    dead after conv1 -> h2 reuses [128V,256V)
    //   h1T bf16 [304V,368V)
    //   w1T bf16 [368V..), w2T, stats, pstats, zpad
    _Float16* sp  = (_Float16*)ws;
    _Float16* tp  = (_Float16*)(ws + (size_t)32 * VOL);
    ushort* featT = (ushort*)(ws + (size_t)128 * VOL);
    float*  h1    = ws;
    float*  h2    = ws + (size_t)128 * VOL;
    ushort* h1T   = (ushort*)(ws + (size_t)304 * VOL);
    float*  w1Tf  = ws + (size_t)368 * VOL;
    ushort* w1T   = (ushort*)w1Tf;
    float*  w2Tf  = w1Tf + 608256;           // 27*128*352 ushorts
    ushort* w2T   = (ushort*)w2Tf;
    float*  stats = w2Tf + 221184;           // 27*128*128 ushorts
    float*  pstats = stats + 256;            // 128*8*2 floats
    float*  zpadf  = pstats + 2048;          // 16B zero pad for conv staging
    const ushort* zpad = (const ushort*)zpadf;

    wprep_kernel<346, 352><<<128, 256, 0, stream>>>(e1w, w1T, zpadf);
    wprep_kernel<128, 128><<<128, 256, 0, stream>>>(e2w, w2T, zpadf);

    proj_l2norm_kernel<<<432, 256, 0, stream>>>(src, psw, psb, sp);
    proj_l2norm_kernel<<<432, 256, 0, stream>>>(tgt, ptw, ptb, tp);
    corr_fused_kernel<<<3456, 256, 0, stream>>>(sp, tp, featT);

    conv3_mfma_kernel<352><<<864, 256, 0, stream>>>(featT, w1T, e1b, zpad, h1);
    chan_stats_part_kernel<<<dim3(128, 8), 256, 0, stream>>>(h1, pstats);
    chan_stats_fin_kernel<<<1, 128, 0, stream>>>(pstats, stats);
    norm_gelu_transpose_kernel<<<dim3(3456, 4), 256, 0, stream>>>(h1, stats, h1T);

    conv3_mfma_kernel<128><<<864, 256, 0, stream>>>(h1T, w2T, e2b, zpad, h2);
    chan_stats_part_kernel<<<dim3(128, 8), 256, 0, stream>>>(h2, pstats);
    chan_stats_fin_kernel<<<1, 128, 0, stream>>>(pstats, stats);
    norm_gelu_kernel<<<(128 * VOL) / 1024, 256, 0, stream>>>(h2, stats, (float*)d_out);
}

// Round 7
// 1026.184 us; speedup vs baseline: 1.3198x; 1.3198x over previous
//
#include <hip/hip_runtime.h>
#include <math.h>
#include <stdint.h>

#define VOL 110592   // 48*48*48
#define CINP 64      // input channels
#define PCH 64       // proj channels

typedef short short8 __attribute__((ext_vector_type(8)));
typedef float floatx4 __attribute__((ext_vector_type(4)));
typedef _Float16 h8 __attribute__((ext_vector_type(8)));
typedef _Float16 h2v __attribute__((ext_vector_type(2)));

__device__ __forceinline__ ushort f2bf(float f) {
    union { float f; uint32_t u; } v; v.f = f;
    uint32_t r = v.u + 0x7FFFu + ((v.u >> 16) & 1u);   // RNE
    return (ushort)(r >> 16);
}

__device__ __forceinline__ float hdot2(h2v a, h2v b, float c) {
#if __has_builtin(__builtin_amdgcn_fdot2)
    return __builtin_amdgcn_fdot2(a, b, c, false);
#else
    return fmaf((float)a[0], (float)b[0], fmaf((float)a[1], (float)b[1], c));
#endif
}

// ---------------------------------------------------------------------------
// 1x1x1 conv (64x64 matvec) + bias + channel L2-normalize. fp16 voxel-major
// output (post-norm values in [-1,1] -> fp16-safe).
__global__ __launch_bounds__(256) void proj_l2norm_kernel(
    const float* __restrict__ x,   // [64][VOL]
    const float* __restrict__ w,   // [64][64]
    const float* __restrict__ b,   // [64]
    _Float16* __restrict__ out)    // [VOL][64]
{
    const int v = blockIdx.x * 256 + threadIdx.x;
    float xr[CINP];
    for (int ci = 0; ci < CINP; ci++)
        xr[ci] = x[(size_t)ci * VOL + v];

    float acc[PCH];
    for (int c = 0; c < PCH; c++) {
        float a = b[c];
        #pragma unroll
        for (int ci = 0; ci < CINP; ci++)
            a = fmaf(w[c * CINP + ci], xr[ci], a);
        acc[c] = a;
    }
    float s = 0.f;
    #pragma unroll
    for (int c = 0; c < PCH; c++) s += acc[c] * acc[c];
    const float inv = 1.0f / fmaxf(sqrtf(s), 1e-12f);
    #pragma unroll
    for (int c = 0; c < PCH; c++)
        out[(size_t)v * PCH + c] = (_Float16)(acc[c] * inv);
}

// ---------------------------------------------------------------------------
// Fused correlation (343 offsets, edge-clamped) + softmax expected-offset.
// This round: per dy-row 8x8 transposed octet reduce — 7 tap-partials per
// lane, 3 select+shuffle stages (7 shfl vs 21), after which lane c8 owns
// the finished dot for tap dx=c8-3. exp + softmax accumulation done only
// by the owner lane (exp count /7, softmax FMAs /8, DS ops /3).
__global__ __launch_bounds__(256) void corr_fused_kernel(
    const _Float16* __restrict__ sp,   // [VOL][64]
    const _Float16* __restrict__ tp,   // [VOL][64]
    ushort* __restrict__ featT)        // [VOL][352] bf16
{
    const int t  = threadIdx.x;
    const int c8 = t & 7;
    const int vg = t >> 3;
    const int v  = blockIdx.x * 32 + vg;
    const int x = v % 48, y = (v / 48) % 48, z = v / 2304;

    __shared__ __align__(16) ushort lds[32 * 360];   // 23 KB

    const h8 s = *(const h8*)(sp + (size_t)v * PCH + c8 * 8);

    // this lane owns tap dx = c8-3 (only c8<7 valid)
    const bool owner = (c8 < 7);
    const float fdx_own = (float)(c8 - 3);
    float ssum = 0.f, e0 = 0.f, e1 = 0.f;

    int k = 0;
    for (int dz = -3; dz <= 3; dz++) {
        const int zb = min(max(z + dz, 0), 47) * 2304;
        const float fdz = (float)dz;
        for (int dy = -3; dy <= 3; dy++) {
            const int rb = zb + min(max(y + dy, 0), 47) * 48;
            const float fdy = (float)dy;
            // issue all 7 loads first (MLP=7)
            h8 tv[7];
            #pragma unroll
            for (int dxi = 0; dxi < 7; dxi++) {
                const int xc = min(max(x + dxi - 3, 0), 47);
                tv[dxi] = *(const h8*)(tp + (size_t)(rb + xc) * PCH + c8 * 8);
            }
            // per-lane channel-chunk partials for the 7 taps
            float p[8];
            #pragma unroll
            for (int dxi = 0; dxi < 7; dxi++) {
                const h8 tvv = tv[dxi];
                float d0 = hdot2((h2v){s[0], s[1]}, (h2v){tvv[0], tvv[1]}, 0.f);
                d0 = hdot2((h2v){s[2], s[3]}, (h2v){tvv[2], tvv[3]}, d0);
                float d1 = hdot2((h2v){s[4], s[5]}, (h2v){tvv[4], tvv[5]}, 0.f);
                d1 = hdot2((h2v){s[6], s[7]}, (h2v){tvv[6], tvv[7]}, d1);
                p[dxi] = d0 + d1;
            }
            p[7] = 0.f;

            // 8x8 transposed reduce across the octet: lane c8 ends with
            // sum over lanes of p[c8] (= full 64-ch dot for tap dx=c8-3).
            float r0, r1, r2, r3;
            {
                const bool hi = (c8 & 1);
                float m0 = hi ? p[0] : p[1];
                float m1 = hi ? p[2] : p[3];
                float m2 = hi ? p[4] : p[5];
                float m3 = hi ? p[6] : p[7];
                m0 = __shfl_xor(m0, 1);
                m1 = __shfl_xor(m1, 1);
                m2 = __shfl_xor(m2, 1);
                m3 = __shfl_xor(m3, 1);
                r0 = (hi ? p[1] : p[0]) + m0;
                r1 = (hi ? p[3] : p[2]) + m1;
                r2 = (hi ? p[5] : p[4]) + m2;
                r3 = (hi ? p[7] : p[6]) + m3;
            }
            float q0, q1;
            {
                const bool hi = (c8 & 2);
                float m0 = hi ? r0 : r1;
                float m1 = hi ? r2 : r3;
                m0 = __shfl_xor(m0, 2);
                m1 = __shfl_xor(m1, 2);
                q0 = (hi ? r1 : r0) + m0;
                q1 = (hi ? r3 : r2) + m1;
            }
            float dot;
            {
                const bool hi = (c8 & 4);
                float m0 = hi ? q0 : q1;
                m0 = __shfl_xor(m0, 4);
                dot = (hi ? q1 : q0) + m0;
            }

            if (owner) {
                lds[vg * 360 + k + c8] = f2bf(dot);
                const float e = __expf(dot);   // |dot|<=1: no max-subtraction
                ssum += e;
                e0 = fmaf(e, fdz, e0);
                e1 = fmaf(e, fdy, e1);
            }
            k += 7;
        }
    }

    // e2 = sum_taps e*dx: per-lane dx is constant -> fdx_own * ssum_lane
    float e2 = fdx_own * ssum;
    // octet all-reduce of the four softmax accumulators (lane7 contributes 0)
    #pragma unroll
    for (int m = 1; m < 8; m <<= 1) {
        ssum += __shfl_xor(ssum, m);
        e0   += __shfl_xor(e0, m);
        e1   += __shfl_xor(e1, m);
        e2   += __shfl_xor(e2, m);
    }

    if (c8 == 0) {
        const float inv = 1.f / ssum;
        lds[vg * 360 + 343] = f2bf(e0 * inv);
        lds[vg * 360 + 344] = f2bf(e1 * inv);
        lds[vg * 360 + 345] = f2bf(e2 * inv);
        #pragma unroll
        for (int j = 346; j < 352; j++) lds[vg * 360 + j] = 0;
    }
    __syncthreads();

    ushort* ob = featT + (size_t)blockIdx.x * 32 * 352;
    #pragma unroll
    for (int j = 0; j < 6; j++) {
        const int idx = t + j * 256;
        if (idx < 1408) {
            const int row = idx / 44, col = (idx % 44) * 8;
            *(int4*)(ob + (size_t)row * 352 + col) = *(const int4*)(&lds[row * 360 + col]);
        }
    }
}

// ---------------------------------------------------------------------------
// Weight pre-transpose: w[128][CIN][27] fp32 -> wT[27][128][CPAD] bf16 (pad 0).
// Block 0 also zero-fills the 16B global pad used by conv staging.
template<int CIN, int CPAD>
__global__ __launch_bounds__(256) void wprep_kernel(
    const float* __restrict__ w, ushort* __restrict__ wTo, float* __restrict__ zp)
{
    if (blockIdx.x == 0 && threadIdx.x < 4) zp[threadIdx.x] = 0.f;
    const int oc = blockIdx.x;
    for (int idx = threadIdx.x; idx < CPAD * 27; idx += 256) {
        const int icp = idx / 27, tap = idx - icp * 27;
        float val = 0.f;
        if (icp < CIN) val = w[((size_t)oc * CIN + icp) * 27 + tap];
        wTo[((size_t)tap * 128 + oc) * CPAD + icp] = f2bf(val);
    }
}

// ---------------------------------------------------------------------------
// Implicit-GEMM 3x3x3 conv via bf16 MFMA (zero padding).
// Round-5 version verbatim (measured 366 us @CPAD=352): global_load_lds
// width-16 staging into LINEAR win[432*32], A-operand register double-buffer,
// #pragma unroll 1 tap loop (full unroll spills — round-6 lesson), XCD-chunked
// bijective block swizzle (FETCH 250->107MB), __launch_bounds__(256,4).
// Register budget is exactly 64 VGPR + 64 AGPR = 128 -> zero headroom.
// Block: 128 voxels (2z x 4y x 16x) x 128 oc, 4 waves.
template<int CPAD>
__global__ __launch_bounds__(256, 4) void conv3_mfma_kernel(
    const ushort* __restrict__ xT,   // [VOL][CPAD] bf16
    const ushort* __restrict__ wT,   // [27][128][CPAD] bf16
    const float* __restrict__ bias,  // [128]
    const ushort* __restrict__ zpad, // 16B of zeros
    float* __restrict__ out)         // [128][VOL] fp32
{
    // XCD-chunked swizzle: grid 864, 8 XCDs -> chunk of 108 contiguous
    // logical blocks per XCD. Bijective since 864 % 8 == 0.
    const int blk = (blockIdx.x % 8) * 108 + (blockIdx.x / 8);
    const int tx = blk % 3, ty = (blk / 3) % 12, tz = blk / 36;
    const int x0 = tx * 16, y0 = ty * 4, z0 = tz * 2;
    const int t = threadIdx.x;
    const int wave = t >> 6;
    const int lane = t & 63;
    const int l = lane & 15;
    const int q = lane >> 4;
    const int ocw = (wave & 1) * 64;
    const int mzw = wave >> 1;

    __shared__ __align__(16) ushort win[432 * 32];   // 27 KB, linear

    // per-lane staging byte offsets into xT (chunk 0), -1 = halo/OOB -> zpad.
    int off[7];
    #pragma unroll
    for (int it = 0; it < 7; it++) {
        const int c = wave + it * 4;
        off[it] = -1;
        if (c < 27) {
            const int i = c * 64 + lane;
            const int p = i >> 2, g = i & 3;
            const int wz = p / 108, pr = p - wz * 108;
            const int wy = pr / 18, wx = pr - wy * 18;
            const int gz = z0 + wz - 1, gy = y0 + wy - 1, gx = x0 + wx - 1;
            if ((unsigned)gx < 48u && (unsigned)gy < 48u && (unsigned)gz < 48u)
                off[it] = ((gz * 2304 + gy * 48 + gx) * CPAD + g * 8) * 2;
        }
    }

    floatx4 acc[4][4];   // acc[oc-subtile j][voxel-subtile mt]
    #pragma unroll
    for (int i = 0; i < 4; i++)
        #pragma unroll
        for (int j = 0; j < 4; j++)
            acc[i][j] = (floatx4){0.f, 0.f, 0.f, 0.f};

    const ushort* wbase = wT + (size_t)(ocw + l) * CPAD + q * 8;
    const int ldsbase = (mzw * 108 + l) * 32 + q * 8;

    const int NCH = CPAD / 32;
    #pragma unroll 1
    for (int ck = 0; ck < NCH; ck++) {
        if (ck) __syncthreads();           // all readers of win done

        // stage chunk ck: 27 x global_load_lds_dwordx4 (linear LDS dest)
        const char* xck = (const char*)xT + (size_t)ck * 64;
        #pragma unroll
        for (int it = 0; it < 7; it++) {
            const int c = wave + it * 4;
            if (c < 27) {
                const ushort* gp = (off[it] >= 0)
                    ? (const ushort*)(xck + off[it])
                    : zpad;
                __builtin_amdgcn_global_load_lds(
                    (const __attribute__((address_space(1))) uint32_t*)gp,
                    (__attribute__((address_space(3))) uint32_t*)(win + c * 512 + lane * 8),
                    16, 0, 0);
            }
        }

        // prologue: tap 0 weights into A0 (L2-resident; drained by barrier)
        const ushort* wck = wbase + ck * 32;
        short8 A0[4], A1[4];
        A0[0] = *(const short8*)(wck);
        A0[1] = *(const short8*)(wck + 16 * CPAD);
        A0[2] = *(const short8*)(wck + 32 * CPAD);
        A0[3] = *(const short8*)(wck + 48 * CPAD);

        __syncthreads();                   // vmcnt(0)+lgkmcnt(0) drain + barrier

        // body(TP): prefetch tap TP+1 into AL, compute tap TP from AU.
#define CONV_BODY(TP, AU, AL)                                              \
        {                                                                  \
            const int tpn_ = (TP) + 1;                                     \
            if (tpn_ < 27) {                                               \
                const ushort* wp_ = wck + (size_t)tpn_ * (128 * CPAD);     \
                AL[0] = *(const short8*)(wp_);                             \
                AL[1] = *(const short8*)(wp_ + 16 * CPAD);                 \
                AL[2] = *(const short8*)(wp_ + 32 * CPAD);                 \
                AL[3] = *(const short8*)(wp_ + 48 * CPAD);                 \
            }                                                              \
            const int dz_ = (TP) / 9;                                      \
            const int dy_ = ((TP) / 3) % 3;                                \
            const int dx_ = (TP) % 3;                                      \
            const int pb_ = ldsbase + (dz_ * 108 + dy_ * 18 + dx_) * 32;   \
            const short8 b0_ = *(const short8*)(&win[pb_ +    0]);         \
            const short8 b1_ = *(const short8*)(&win[pb_ +  576]);         \
            const short8 b2_ = *(const short8*)(&win[pb_ + 1152]);         \
            const short8 b3_ = *(const short8*)(&win[pb_ + 1728]);         \
            acc[0][0] = __builtin_amdgcn_mfma_f32_16x16x32_bf16(AU[0], b0_, acc[0][0], 0, 0, 0); \
            acc[1][0] = __builtin_amdgcn_mfma_f32_16x16x32_bf16(AU[1], b0_, acc[1][0], 0, 0, 0); \
            acc[2][0] = __builtin_amdgcn_mfma_f32_16x16x32_bf16(AU[2], b0_, acc[2][0], 0, 0, 0); \
            acc[3][0] = __builtin_amdgcn_mfma_f32_16x16x32_bf16(AU[3], b0_, acc[3][0], 0, 0, 0); \
            acc[0][1] = __builtin_amdgcn_mfma_f32_16x16x32_bf16(AU[0], b1_, acc[0][1], 0, 0, 0); \
            acc[1][1] = __builtin_amdgcn_mfma_f32_16x16x32_bf16(AU[1], b1_, acc[1][1], 0, 0, 0); \
            acc[2][1] = __builtin_amdgcn_mfma_f32_16x16x32_bf16(AU[2], b1_, acc[2][1], 0, 0, 0); \
            acc[3][1] = __builtin_amdgcn_mfma_f32_16x16x32_bf16(AU[3], b1_, acc[3][1], 0, 0, 0); \
            acc[0][2] = __builtin_amdgcn_mfma_f32_16x16x32_bf16(AU[0], b2_, acc[0][2], 0, 0, 0); \
            acc[1][2] = __builtin_amdgcn_mfma_f32_16x16x32_bf16(AU[1], b2_, acc[1][2], 0, 0, 0); \
            acc[2][2] = __builtin_amdgcn_mfma_f32_16x16x32_bf16(AU[2], b2_, acc[2][2], 0, 0, 0); \
            acc[3][2] = __builtin_amdgcn_mfma_f32_16x16x32_bf16(AU[3], b2_, acc[3][2], 0, 0, 0); \
            acc[0][3] = __builtin_amdgcn_mfma_f32_16x16x32_bf16(AU[0], b3_, acc[0][3], 0, 0, 0); \
            acc[1][3] = __builtin_amdgcn_mfma_f32_16x16x32_bf16(AU[1], b3_, acc[1][3], 0, 0, 0); \
            acc[2][3] = __builtin_amdgcn_mfma_f32_16x16x32_bf16(AU[2], b3_, acc[2][3], 0, 0, 0); \
            acc[3][3] = __builtin_amdgcn_mfma_f32_16x16x32_bf16(AU[3], b3_, acc[3][3], 0, 0, 0); \
        }

        #pragma unroll 1
        for (int tg = 0; tg < 13; tg++) {
            const int tp = tg * 2;
            CONV_BODY(tp, A0, A1);
            CONV_BODY(tp + 1, A1, A0);
        }
        CONV_BODY(26, A0, A1);
#undef CONV_BODY
    }

    #pragma unroll
    for (int nt = 0; nt < 4; nt++) {
        const int ocb = ocw + nt * 16 + q * 4;
        const float4 bv = *(const float4*)(bias + ocb);
        #pragma unroll
        for (int mt = 0; mt < 4; mt++) {
            const int v = (z0 + mzw) * 2304 + (y0 + mt) * 48 + x0 + l;
            out[(size_t)(ocb + 0) * VOL + v] = acc[nt][mt][0] + bv.x;
            out[(size_t)(ocb + 1) * VOL + v] = acc[nt][mt][1] + bv.y;
            out[(size_t)(ocb + 2) * VOL + v] = acc[nt][mt][2] + bv.z;
            out[(size_t)(ocb + 3) * VOL + v] = acc[nt][mt][3] + bv.w;
        }
    }
}

// ---------------------------------------------------------------------------
// Two-phase per-channel stats. Phase 1: grid (128, 8) partial sums.
__global__ __launch_bounds__(256) void chan_stats_part_kernel(
    const float* __restrict__ x, float* __restrict__ pstats /* [128][8][2] */)
{
    const int c = blockIdx.x, g = blockIdx.y;
    const float4* p = (const float4*)(x + (size_t)c * VOL) + g * 3456;
    float s = 0.f, s2 = 0.f;
    #pragma unroll
    for (int j = 0; j < 14; j++) {
        const int i = threadIdx.x + j * 256;
        if (i < 3456) {
            const float4 v = p[i];
            s += v.x + v.y + v.z + v.w;
            s2 = fmaf(v.x, v.x, fmaf(v.y, v.y, fmaf(v.z, v.z, fmaf(v.w, v.w, s2))));
        }
    }
    s  += __shfl_down(s, 32);  s  += __shfl_down(s, 16);
    s  += __shfl_down(s, 8);   s  += __shfl_down(s, 4);
    s  += __shfl_down(s, 2);   s  += __shfl_down(s, 1);
    s2 += __shfl_down(s2, 32); s2 += __shfl_down(s2, 16);
    s2 += __shfl_down(s2, 8);  s2 += __shfl_down(s2, 4);
    s2 += __shfl_down(s2, 2);  s2 += __shfl_down(s2, 1);
    __shared__ float rs[4], rs2[4];
    if ((threadIdx.x & 63) == 0) {
        rs[threadIdx.x >> 6] = s;
        rs2[threadIdx.x >> 6] = s2;
    }
    __syncthreads();
    if (threadIdx.x == 0) {
        pstats[(c * 8 + g) * 2]     = rs[0] + rs[1] + rs[2] + rs[3];
        pstats[(c * 8 + g) * 2 + 1] = rs2[0] + rs2[1] + rs2[2] + rs2[3];
    }
}

// Phase 2: 1 block, 128 threads -> mean/rstd.
__global__ __launch_bounds__(128) void chan_stats_fin_kernel(
    const float* __restrict__ pstats, float* __restrict__ stats /* [128][2] */)
{
    const int c = threadIdx.x;
    float s = 0.f, s2 = 0.f;
    #pragma unroll
    for (int g = 0; g < 8; g++) {
        s  += pstats[(c * 8 + g) * 2];
        s2 += pstats[(c * 8 + g) * 2 + 1];
    }
    const float mean = s / (float)VOL;
    const float var  = s2 / (float)VOL - mean * mean;
    stats[c * 2]     = mean;
    stats[c * 2 + 1] = rsqrtf(var + 1e-5f);
}

__device__ __forceinline__ float gelu_exact(float h)
{
    return 0.5f * h * (1.f + erff(h * 0.70710678118654752f));
}

// Elementwise instance-norm apply + exact GELU (final output, fp32).
__global__ __launch_bounds__(256) void norm_gelu_kernel(
    const float* __restrict__ x, const float* __restrict__ stats,
    float* __restrict__ out)
{
    const size_t i = (size_t)blockIdx.x * 256 + threadIdx.x;  // float4 index
    const int c = (int)(i / (VOL / 4));
    const float mean = stats[c * 2], rstd = stats[c * 2 + 1];
    const float4 xv = ((const float4*)x)[i];
    float4 o;
    o.x = gelu_exact((xv.x - mean) * rstd);
    o.y = gelu_exact((xv.y - mean) * rstd);
    o.z = gelu_exact((xv.z - mean) * rstd);
    o.w = gelu_exact((xv.w - mean) * rstd);
    ((float4*)out)[i] = o;
}

// ---------------------------------------------------------------------------
// Fused: instance-norm apply + GELU + transpose [128][VOL] fp32 -> [VOL][128]
// bf16 (32x32 LDS tiles).
__global__ __launch_bounds__(256) void norm_gelu_transpose_kernel(
    const float* __restrict__ x, const float* __restrict__ stats,
    ushort* __restrict__ outT)
{
    __shared__ float tile[32][33];
    const int v0 = blockIdx.x * 32;
    const int c0 = blockIdx.y * 32;
    const int t = threadIdx.x;
    const int vl = t & 31, cl = t >> 5;
    #pragma unroll
    for (int i = 0; i < 4; i++) {
        const int c = c0 + cl + i * 8;
        const float mean = stats[c * 2], rstd = stats[c * 2 + 1];
        const float val = x[(size_t)c * VOL + v0 + vl];
        tile[cl + i * 8][vl] = gelu_exact((val - mean) * rstd);
    }
    __syncthreads();
    const int vw = t >> 3, cg = t & 7;
    ushort4 o;
    o.x = f2bf(tile[cg * 4 + 0][vw]);
    o.y = f2bf(tile[cg * 4 + 1][vw]);
    o.z = f2bf(tile[cg * 4 + 2][vw]);
    o.w = f2bf(tile[cg * 4 + 3][vw]);
    *(ushort4*)(outT + (size_t)(v0 + vw) * 128 + c0 + cg * 4) = o;
}

// ---------------------------------------------------------------------------
extern "C" void kernel_launch(void* const* d_in, const int* in_sizes, int n_in,
                              void* d_out, int out_size, void* d_ws, size_t ws_size,
                              hipStream_t stream)
{
    const float* src = (const float*)d_in[0];
    const float* tgt = (const float*)d_in[1];
    const float* psw = (const float*)d_in[2];
    const float* psb = (const float*)d_in[3];
    const float* ptw = (const float*)d_in[4];
    const float* ptb = (const float*)d_in[5];
    const float* e1w = (const float*)d_in[6];
    const float* e1b = (const float*)d_in[7];
    const float* e2w = (const float*)d_in[8];
    const float* e2b = (const float*)d_in[9];

    float* ws = (float*)d_ws;
    // Workspace (float-unit offsets; V = VOL):
    //   sp/tp fp16 [0,64V)        dead after corr -> h1 (fp32) reuses [0,128V)
    //   featT bf16 [128V,304V)    dead after conv1 -> h2 reuses [128V,256V)
    //   h1T bf16 [304V,368V)
    //   w1T bf16 [368V..), w2T, stats, pstats, zpad
    _Float16* sp  = (_Float16*)ws;
    _Float16* tp  = (_Float16*)(ws + (size_t)32 * VOL);
    ushort* featT = (ushort*)(ws + (size_t)128 * VOL);
    float*  h1    = ws;
    float*  h2    = ws + (size_t)128 * VOL;
    ushort* h1T   = (ushort*)(ws + (size_t)304 * VOL);
    float*  w1Tf  = ws + (size_t)368 * VOL;
    ushort* w1T   = (ushort*)w1Tf;
    float*  w2Tf  = w1Tf + 608256;           // 27*128*352 ushorts
    ushort* w2T   = (ushort*)w2Tf;
    float*  stats = w2Tf + 221184;           // 27*128*128 ushorts
    float*  pstats = stats + 256;            // 128*8*2 floats
    float*  zpadf  = pstats + 2048;          // 16B zero pad for conv staging
    const ushort* zpad = (const ushort*)zpadf;

    wprep_kernel<346, 352><<<128, 256, 0, stream>>>(e1w, w1T, zpadf);
    wprep_kernel<128, 128><<<128, 256, 0, stream>>>(e2w, w2T, zpadf);

    proj_l2norm_kernel<<<432, 256, 0, stream>>>(src, psw, psb, sp);
    proj_l2norm_kernel<<<432, 256, 0, stream>>>(tgt, ptw, ptb, tp);
    corr_fused_kernel<<<3456, 256, 0, stream>>>(sp, tp, featT);

    conv3_mfma_kernel<352><<<864, 256, 0, stream>>>(featT, w1T, e1b, zpad, h1);
    chan_stats_part_kernel<<<dim3(128, 8), 256, 0, stream>>>(h1, pstats);
    chan_stats_fin_kernel<<<1, 128, 0, stream>>>(pstats, stats);
    norm_gelu_transpose_kernel<<<dim3(3456, 4), 256, 0, stream>>>(h1, stats, h1T);

    conv3_mfma_kernel<128><<<864, 256, 0, stream>>>(h1T, w2T, e2b, zpad, h2);
    chan_stats_part_kernel<<<dim3(128, 8), 256, 0, stream>>>(h2, pstats);
    chan_stats_fin_kernel<<<1, 128, 0, stream>>>(pstats, stats);
    norm_gelu_kernel<<<(128 * VOL) / 1024, 256, 0, stream>>>(h2, stats, (float*)d_out);
}

// Round 8
// 1019.268 us; speedup vs baseline: 1.3288x; 1.0068x over previous
//
#include <hip/hip_runtime.h>
#include <math.h>
#include <stdint.h>

#define VOL 110592   // 48*48*48
#define CINP 64      // input channels
#define PCH 64       // proj channels

typedef short short8 __attribute__((ext_vector_type(8)));
typedef float floatx4 __attribute__((ext_vector_type(4)));
typedef _Float16 h8 __attribute__((ext_vector_type(8)));
typedef _Float16 h2v __attribute__((ext_vector_type(2)));

__device__ __forceinline__ ushort f2bf(float f) {
    union { float f; uint32_t u; } v; v.f = f;
    uint32_t r = v.u + 0x7FFFu + ((v.u >> 16) & 1u);   // RNE
    return (ushort)(r >> 16);
}

__device__ __forceinline__ float hdot2(h2v a, h2v b, float c) {
#if __has_builtin(__builtin_amdgcn_fdot2)
    return __builtin_amdgcn_fdot2(a, b, c, false);
#else
    return fmaf((float)a[0], (float)b[0], fmaf((float)a[1], (float)b[1], c));
#endif
}

// ---------------------------------------------------------------------------
// 1x1x1 conv (64x64 matvec) + bias + channel L2-normalize. fp16 voxel-major
// output (post-norm values in [-1,1] -> fp16-safe).
__global__ __launch_bounds__(256) void proj_l2norm_kernel(
    const float* __restrict__ x,   // [64][VOL]
    const float* __restrict__ w,   // [64][64]
    const float* __restrict__ b,   // [64]
    _Float16* __restrict__ out)    // [VOL][64]
{
    const int v = blockIdx.x * 256 + threadIdx.x;
    float xr[CINP];
    for (int ci = 0; ci < CINP; ci++)
        xr[ci] = x[(size_t)ci * VOL + v];

    float acc[PCH];
    for (int c = 0; c < PCH; c++) {
        float a = b[c];
        #pragma unroll
        for (int ci = 0; ci < CINP; ci++)
            a = fmaf(w[c * CINP + ci], xr[ci], a);
        acc[c] = a;
    }
    float s = 0.f;
    #pragma unroll
    for (int c = 0; c < PCH; c++) s += acc[c] * acc[c];
    const float inv = 1.0f / fmaxf(sqrtf(s), 1e-12f);
    #pragma unroll
    for (int c = 0; c < PCH; c++)
        out[(size_t)v * PCH + c] = (_Float16)(acc[c] * inv);
}

// ---------------------------------------------------------------------------
// Fused correlation (343 offsets, edge-clamped) + softmax expected-offset.
// 8x8 transposed octet reduce (round-7 win): lane c8 owns tap dx=c8-3.
__global__ __launch_bounds__(256) void corr_fused_kernel(
    const _Float16* __restrict__ sp,   // [VOL][64]
    const _Float16* __restrict__ tp,   // [VOL][64]
    ushort* __restrict__ featT)        // [VOL][352] bf16
{
    const int t  = threadIdx.x;
    const int c8 = t & 7;
    const int vg = t >> 3;
    const int v  = blockIdx.x * 32 + vg;
    const int x = v % 48, y = (v / 48) % 48, z = v / 2304;

    __shared__ __align__(16) ushort lds[32 * 360];   // 23 KB

    const h8 s = *(const h8*)(sp + (size_t)v * PCH + c8 * 8);

    const bool owner = (c8 < 7);
    const float fdx_own = (float)(c8 - 3);
    float ssum = 0.f, e0 = 0.f, e1 = 0.f;

    int k = 0;
    for (int dz = -3; dz <= 3; dz++) {
        const int zb = min(max(z + dz, 0), 47) * 2304;
        const float fdz = (float)dz;
        for (int dy = -3; dy <= 3; dy++) {
            const int rb = zb + min(max(y + dy, 0), 47) * 48;
            const float fdy = (float)dy;
            h8 tv[7];
            #pragma unroll
            for (int dxi = 0; dxi < 7; dxi++) {
                const int xc = min(max(x + dxi - 3, 0), 47);
                tv[dxi] = *(const h8*)(tp + (size_t)(rb + xc) * PCH + c8 * 8);
            }
            float p[8];
            #pragma unroll
            for (int dxi = 0; dxi < 7; dxi++) {
                const h8 tvv = tv[dxi];
                float d0 = hdot2((h2v){s[0], s[1]}, (h2v){tvv[0], tvv[1]}, 0.f);
                d0 = hdot2((h2v){s[2], s[3]}, (h2v){tvv[2], tvv[3]}, d0);
                float d1 = hdot2((h2v){s[4], s[5]}, (h2v){tvv[4], tvv[5]}, 0.f);
                d1 = hdot2((h2v){s[6], s[7]}, (h2v){tvv[6], tvv[7]}, d1);
                p[dxi] = d0 + d1;
            }
            p[7] = 0.f;

            float r0, r1, r2, r3;
            {
                const bool hi = (c8 & 1);
                float m0 = hi ? p[0] : p[1];
                float m1 = hi ? p[2] : p[3];
                float m2 = hi ? p[4] : p[5];
                float m3 = hi ? p[6] : p[7];
                m0 = __shfl_xor(m0, 1);
                m1 = __shfl_xor(m1, 1);
                m2 = __shfl_xor(m2, 1);
                m3 = __shfl_xor(m3, 1);
                r0 = (hi ? p[1] : p[0]) + m0;
                r1 = (hi ? p[3] : p[2]) + m1;
                r2 = (hi ? p[5] : p[4]) + m2;
                r3 = (hi ? p[7] : p[6]) + m3;
            }
            float q0, q1;
            {
                const bool hi = (c8 & 2);
                float m0 = hi ? r0 : r1;
                float m1 = hi ? r2 : r3;
                m0 = __shfl_xor(m0, 2);
                m1 = __shfl_xor(m1, 2);
                q0 = (hi ? r1 : r0) + m0;
                q1 = (hi ? r3 : r2) + m1;
            }
            float dot;
            {
                const bool hi = (c8 & 4);
                float m0 = hi ? q0 : q1;
                m0 = __shfl_xor(m0, 4);
                dot = (hi ? q1 : q0) + m0;
            }

            if (owner) {
                lds[vg * 360 + k + c8] = f2bf(dot);
                const float e = __expf(dot);   // |dot|<=1: no max-subtraction
                ssum += e;
                e0 = fmaf(e, fdz, e0);
                e1 = fmaf(e, fdy, e1);
            }
            k += 7;
        }
    }

    float e2 = fdx_own * ssum;
    #pragma unroll
    for (int m = 1; m < 8; m <<= 1) {
        ssum += __shfl_xor(ssum, m);
        e0   += __shfl_xor(e0, m);
        e1   += __shfl_xor(e1, m);
        e2   += __shfl_xor(e2, m);
    }

    if (c8 == 0) {
        const float inv = 1.f / ssum;
        lds[vg * 360 + 343] = f2bf(e0 * inv);
        lds[vg * 360 + 344] = f2bf(e1 * inv);
        lds[vg * 360 + 345] = f2bf(e2 * inv);
        #pragma unroll
        for (int j = 346; j < 352; j++) lds[vg * 360 + j] = 0;
    }
    __syncthreads();

    ushort* ob = featT + (size_t)blockIdx.x * 32 * 352;
    #pragma unroll
    for (int j = 0; j < 6; j++) {
        const int idx = t + j * 256;
        if (idx < 1408) {
            const int row = idx / 44, col = (idx % 44) * 8;
            *(int4*)(ob + (size_t)row * 352 + col) = *(const int4*)(&lds[row * 360 + col]);
        }
    }
}

// ---------------------------------------------------------------------------
// Weight pre-transpose: w[128][CIN][27] fp32 -> wT[27][128][CPAD] bf16 (pad 0).
// Block 0 also zero-fills the 16B global pad used by conv staging.
template<int CIN, int CPAD>
__global__ __launch_bounds__(256) void wprep_kernel(
    const float* __restrict__ w, ushort* __restrict__ wTo, float* __restrict__ zp)
{
    if (blockIdx.x == 0 && threadIdx.x < 4) zp[threadIdx.x] = 0.f;
    const int oc = blockIdx.x;
    for (int idx = threadIdx.x; idx < CPAD * 27; idx += 256) {
        const int icp = idx / 27, tap = idx - icp * 27;
        float val = 0.f;
        if (icp < CIN) val = w[((size_t)oc * CIN + icp) * 27 + tap];
        wTo[((size_t)tap * 128 + oc) * CPAD + icp] = f2bf(val);
    }
}

// ---------------------------------------------------------------------------
// Implicit-GEMM 3x3x3 conv via bf16 MFMA (zero padding).
// This round: LDS DOUBLE-BUFFER + counted-vmcnt staging overlap + B-side
// register double-buffer.
//  - win[2][432*32] (54KB): chunk ck+1's 27 global_load_lds are issued at
//    the START of chunk ck's compute into the other buffer — they stay in
//    flight under the whole 27-tap MFMA phase (no serialized drain).
//  - ONE barrier per chunk (was 2): protects buffer swap; by barrier time
//    the staging loads have landed, so the implicit vmcnt(0) is cheap.
//  - B-fragments (LDS reads) double-buffered across taps, like A: removes
//    per-tap exposed LDS latency. Possible now because 2 blocks/CU doubles
//    the per-wave register budget (launch_bounds(256,2)).
//  - MFMA accumulation order per acc element unchanged (numerics identical).
// Trade: occupancy 16 -> 8 waves/CU. Failure signature: conv1 >= 420us.
// Block: 128 voxels (2z x 4y x 16x) x 128 oc, 4 waves.
template<int CPAD>
__global__ __launch_bounds__(256, 2) void conv3_mfma_kernel(
    const ushort* __restrict__ xT,   // [VOL][CPAD] bf16
    const ushort* __restrict__ wT,   // [27][128][CPAD] bf16
    const float* __restrict__ bias,  // [128]
    const ushort* __restrict__ zpad, // 16B of zeros
    float* __restrict__ out)         // [128][VOL] fp32
{
    // XCD-chunked swizzle: grid 864, 8 XCDs -> 108 contiguous blocks per XCD.
    const int blk = (blockIdx.x % 8) * 108 + (blockIdx.x / 8);
    const int tx = blk % 3, ty = (blk / 3) % 12, tz = blk / 36;
    const int x0 = tx * 16, y0 = ty * 4, z0 = tz * 2;
    const int t = threadIdx.x;
    const int wave = t >> 6;
    const int lane = t & 63;
    const int l = lane & 15;
    const int q = lane >> 4;
    const int ocw = (wave & 1) * 64;
    const int mzw = wave >> 1;

    __shared__ __align__(16) ushort win[2][432 * 32];   // 54KB double buffer

    // per-lane staging byte offsets into xT (chunk 0), -1 = halo/OOB -> zpad.
    int off[7];
    #pragma unroll
    for (int it = 0; it < 7; it++) {
        const int c = wave + it * 4;
        off[it] = -1;
        if (c < 27) {
            const int i = c * 64 + lane;
            const int p = i >> 2, g = i & 3;
            const int wz = p / 108, pr = p - wz * 108;
            const int wy = pr / 18, wx = pr - wy * 18;
            const int gz = z0 + wz - 1, gy = y0 + wy - 1, gx = x0 + wx - 1;
            if ((unsigned)gx < 48u && (unsigned)gy < 48u && (unsigned)gz < 48u)
                off[it] = ((gz * 2304 + gy * 48 + gx) * CPAD + g * 8) * 2;
        }
    }

    floatx4 acc[4][4];   // acc[oc-subtile j][voxel-subtile mt]
    #pragma unroll
    for (int i = 0; i < 4; i++)
        #pragma unroll
        for (int j = 0; j < 4; j++)
            acc[i][j] = (floatx4){0.f, 0.f, 0.f, 0.f};

    const ushort* wbase = wT + (size_t)(ocw + l) * CPAD + q * 8;
    const int ldsbase = (mzw * 108 + l) * 32 + q * 8;

    // stage chunk CK into LDS buffer BUFP (27 x global_load_lds_dwordx4)
#define STAGE(CK, BUFP)                                                    \
    {                                                                      \
        const char* xck_ = (const char*)xT + (size_t)(CK) * 64;            \
        _Pragma("unroll")                                                  \
        for (int it_ = 0; it_ < 7; it_++) {                                \
            const int c_ = wave + it_ * 4;                                 \
            if (c_ < 27) {                                                 \
                const ushort* gp_ = (off[it_] >= 0)                        \
                    ? (const ushort*)(xck_ + off[it_]) : zpad;             \
                __builtin_amdgcn_global_load_lds(                          \
                    (const __attribute__((address_space(1))) uint32_t*)gp_,\
                    (__attribute__((address_space(3))) uint32_t*)((BUFP) + c_ * 512 + lane * 8), \
                    16, 0, 0);                                             \
            }                                                              \
        }                                                                  \
    }

    const int NCH = CPAD / 32;

    // prologue: stage chunk 0 into buffer 0
    STAGE(0, &win[0][0]);
    __syncthreads();

    #pragma unroll 1
    for (int ck = 0; ck < NCH; ck++) {
        const ushort* cbuf = &win[ck & 1][0];
        ushort* nbuf = &win[(ck + 1) & 1][0];
        const ushort* wck = wbase + ck * 32;

        // A prologue (tap 0 weights) issued BEFORE staging so the first
        // MFMA's vmcnt wait doesn't queue behind the 27 staging loads.
        short8 A0[4], A1[4];
        A0[0] = *(const short8*)(wck);
        A0[1] = *(const short8*)(wck + 16 * CPAD);
        A0[2] = *(const short8*)(wck + 32 * CPAD);
        A0[3] = *(const short8*)(wck + 48 * CPAD);

        // B prologue (tap 0 fragments from current buffer)
        short8 B0[4], B1[4];
        B0[0] = *(const short8*)(&cbuf[ldsbase +    0]);
        B0[1] = *(const short8*)(&cbuf[ldsbase +  576]);
        B0[2] = *(const short8*)(&cbuf[ldsbase + 1152]);
        B0[3] = *(const short8*)(&cbuf[ldsbase + 1728]);

        // issue next-chunk staging; stays in flight under this chunk's MFMAs
        if (ck + 1 < NCH) STAGE(ck + 1, nbuf);

        // body(TP): prefetch tap TP+1 (A from global, B from LDS) into the
        // alternate registers, compute tap TP from the current ones.
#define CONV_BODY(TP, AU, AL, BU, BL)                                      \
        {                                                                  \
            const int tpn_ = (TP) + 1;                                     \
            if (tpn_ < 27) {                                               \
                const ushort* wp_ = wck + (size_t)tpn_ * (128 * CPAD);     \
                AL[0] = *(const short8*)(wp_);                             \
                AL[1] = *(const short8*)(wp_ + 16 * CPAD);                 \
                AL[2] = *(const short8*)(wp_ + 32 * CPAD);                 \
                AL[3] = *(const short8*)(wp_ + 48 * CPAD);                 \
                const int dzn_ = tpn_ / 9;                                 \
                const int dyn_ = (tpn_ / 3) % 3;                           \
                const int dxn_ = tpn_ % 3;                                 \
                const int pbn_ = ldsbase + (dzn_ * 108 + dyn_ * 18 + dxn_) * 32; \
                BL[0] = *(const short8*)(&cbuf[pbn_ +    0]);              \
                BL[1] = *(const short8*)(&cbuf[pbn_ +  576]);              \
                BL[2] = *(const short8*)(&cbuf[pbn_ + 1152]);              \
                BL[3] = *(const short8*)(&cbuf[pbn_ + 1728]);              \
            }                                                              \
            acc[0][0] = __builtin_amdgcn_mfma_f32_16x16x32_bf16(AU[0], BU[0], acc[0][0], 0, 0, 0); \
            acc[1][0] = __builtin_amdgcn_mfma_f32_16x16x32_bf16(AU[1], BU[0], acc[1][0], 0, 0, 0); \
            acc[2][0] = __builtin_amdgcn_mfma_f32_16x16x32_bf16(AU[2], BU[0], acc[2][0], 0, 0, 0); \
            acc[3][0] = __builtin_amdgcn_mfma_f32_16x16x32_bf16(AU[3], BU[0], acc[3][0], 0, 0, 0); \
            acc[0][1] = __builtin_amdgcn_mfma_f32_16x16x32_bf16(AU[0], BU[1], acc[0][1], 0, 0, 0); \
            acc[1][1] = __builtin_amdgcn_mfma_f32_16x16x32_bf16(AU[1], BU[1], acc[1][1], 0, 0, 0); \
            acc[2][1] = __builtin_amdgcn_mfma_f32_16x16x32_bf16(AU[2], BU[1], acc[2][1], 0, 0, 0); \
            acc[3][1] = __builtin_amdgcn_mfma_f32_16x16x32_bf16(AU[3], BU[1], acc[3][1], 0, 0, 0); \
            acc[0][2] = __builtin_amdgcn_mfma_f32_16x16x32_bf16(AU[0], BU[2], acc[0][2], 0, 0, 0); \
            acc[1][2] = __builtin_amdgcn_mfma_f32_16x16x32_bf16(AU[1], BU[2], acc[1][2], 0, 0, 0); \
            acc[2][2] = __builtin_amdgcn_mfma_f32_16x16x32_bf16(AU[2], BU[2], acc[2][2], 0, 0, 0); \
            acc[3][2] = __builtin_amdgcn_mfma_f32_16x16x32_bf16(AU[3], BU[2], acc[3][2], 0, 0, 0); \
            acc[0][3] = __builtin_amdgcn_mfma_f32_16x16x32_bf16(AU[0], BU[3], acc[0][3], 0, 0, 0); \
            acc[1][3] = __builtin_amdgcn_mfma_f32_16x16x32_bf16(AU[1], BU[3], acc[1][3], 0, 0, 0); \
            acc[2][3] = __builtin_amdgcn_mfma_f32_16x16x32_bf16(AU[2], BU[3], acc[2][3], 0, 0, 0); \
            acc[3][3] = __builtin_amdgcn_mfma_f32_16x16x32_bf16(AU[3], BU[3], acc[3][3], 0, 0, 0); \
        }

        #pragma unroll 1
        for (int tg = 0; tg < 13; tg++) {
            const int tp = tg * 2;
            CONV_BODY(tp, A0, A1, B0, B1);
            CONV_BODY(tp + 1, A1, A0, B1, B0);
        }
        CONV_BODY(26, A0, A1, B0, B1);
#undef CONV_BODY

        // one barrier per chunk: all reads of cbuf done; staging into nbuf
        // landed (implicit vmcnt(0) here is cheap — loads had a whole chunk
        // of flight time).
        __syncthreads();
    }
#undef STAGE

    #pragma unroll
    for (int nt = 0; nt < 4; nt++) {
        const int ocb = ocw + nt * 16 + q * 4;
        const float4 bv = *(const float4*)(bias + ocb);
        #pragma unroll
        for (int mt = 0; mt < 4; mt++) {
            const int v = (z0 + mzw) * 2304 + (y0 + mt) * 48 + x0 + l;
            out[(size_t)(ocb + 0) * VOL + v] = acc[nt][mt][0] + bv.x;
            out[(size_t)(ocb + 1) * VOL + v] = acc[nt][mt][1] + bv.y;
            out[(size_t)(ocb + 2) * VOL + v] = acc[nt][mt][2] + bv.z;
            out[(size_t)(ocb + 3) * VOL + v] = acc[nt][mt][3] + bv.w;
        }
    }
}

// ---------------------------------------------------------------------------
// Two-phase per-channel stats. Phase 1: grid (128, 8) partial sums.
__global__ __launch_bounds__(256) void chan_stats_part_kernel(
    const float* __restrict__ x, float* __restrict__ pstats /* [128][8][2] */)
{
    const int c = blockIdx.x, g = blockIdx.y;
    const float4* p = (const float4*)(x + (size_t)c * VOL) + g * 3456;
    float s = 0.f, s2 = 0.f;
    #pragma unroll
    for (int j = 0; j < 14; j++) {
        const int i = threadIdx.x + j * 256;
        if (i < 3456) {
            const float4 v = p[i];
            s += v.x + v.y + v.z + v.w;
            s2 = fmaf(v.x, v.x, fmaf(v.y, v.y, fmaf(v.z, v.z, fmaf(v.w, v.w, s2))));
        }
    }
    s  += __shfl_down(s, 32);  s  += __shfl_down(s, 16);
    s  += __shfl_down(s, 8);   s  += __shfl_down(s, 4);
    s  += __shfl_down(s, 2);   s  += __shfl_down(s, 1);
    s2 += __shfl_down(s2, 32); s2 += __shfl_down(s2, 16);
    s2 += __shfl_down(s2, 8);  s2 += __shfl_down(s2, 4);
    s2 += __shfl_down(s2, 2);  s2 += __shfl_down(s2, 1);
    __shared__ float rs[4], rs2[4];
    if ((threadIdx.x & 63) == 0) {
        rs[threadIdx.x >> 6] = s;
        rs2[threadIdx.x >> 6] = s2;
    }
    __syncthreads();
    if (threadIdx.x == 0) {
        pstats[(c * 8 + g) * 2]     = rs[0] + rs[1] + rs[2] + rs[3];
        pstats[(c * 8 + g) * 2 + 1] = rs2[0] + rs2[1] + rs2[2] + rs2[3];
    }
}

// Phase 2: 1 block, 128 threads -> mean/rstd.
__global__ __launch_bounds__(128) void chan_stats_fin_kernel(
    const float* __restrict__ pstats, float* __restrict__ stats /* [128][2] */)
{
    const int c = threadIdx.x;
    float s = 0.f, s2 = 0.f;
    #pragma unroll
    for (int g = 0; g < 8; g++) {
        s  += pstats[(c * 8 + g) * 2];
        s2 += pstats[(c * 8 + g) * 2 + 1];
    }
    const float mean = s / (float)VOL;
    const float var  = s2 / (float)VOL - mean * mean;
    stats[c * 2]     = mean;
    stats[c * 2 + 1] = rsqrtf(var + 1e-5f);
}

__device__ __forceinline__ float gelu_exact(float h)
{
    return 0.5f * h * (1.f + erff(h * 0.70710678118654752f));
}

// Elementwise instance-norm apply + exact GELU (final output, fp32).
__global__ __launch_bounds__(256) void norm_gelu_kernel(
    const float* __restrict__ x, const float* __restrict__ stats,
    float* __restrict__ out)
{
    const size_t i = (size_t)blockIdx.x * 256 + threadIdx.x;  // float4 index
    const int c = (int)(i / (VOL / 4));
    const float mean = stats[c * 2], rstd = stats[c * 2 + 1];
    const float4 xv = ((const float4*)x)[i];
    float4 o;
    o.x = gelu_exact((xv.x - mean) * rstd);
    o.y = gelu_exact((xv.y - mean) * rstd);
    o.z = gelu_exact((xv.z - mean) * rstd);
    o.w = gelu_exact((xv.w - mean) * rstd);
    ((float4*)out)[i] = o;
}

// ---------------------------------------------------------------------------
// Fused: instance-norm apply + GELU + transpose [128][VOL] fp32 -> [VOL][128]
// bf16 (32x32 LDS tiles).
__global__ __launch_bounds__(256) void norm_gelu_transpose_kernel(
    const float* __restrict__ x, const float* __restrict__ stats,
    ushort* __restrict__ outT)
{
    __shared__ float tile[32][33];
    const int v0 = blockIdx.x * 32;
    const int c0 = blockIdx.y * 32;
    const int t = threadIdx.x;
    const int vl = t & 31, cl = t >> 5;
    #pragma unroll
    for (int i = 0; i < 4; i++) {
        const int c = c0 + cl + i * 8;
        const float mean = stats[c * 2], rstd = stats[c * 2 + 1];
        const float val = x[(size_t)c * VOL + v0 + vl];
        tile[cl + i * 8][vl] = gelu_exact((val - mean) * rstd);
    }
    __syncthreads();
    const int vw = t >> 3, cg = t & 7;
    ushort4 o;
    o.x = f2bf(tile[cg * 4 + 0][vw]);
    o.y = f2bf(tile[cg * 4 + 1][vw]);
    o.z = f2bf(tile[cg * 4 + 2][vw]);
    o.w = f2bf(tile[cg * 4 + 3][vw]);
    *(ushort4*)(outT + (size_t)(v0 + vw) * 128 + c0 + cg * 4) = o;
}

// ---------------------------------------------------------------------------
extern "C" void kernel_launch(void* const* d_in, const int* in_sizes, int n_in,
                              void* d_out, int out_size, void* d_ws, size_t ws_size,
                              hipStream_t stream)
{
    const float* src = (const float*)d_in[0];
    const float* tgt = (const float*)d_in[1];
    const float* psw = (const float*)d_in[2];
    const float* psb = (const float*)d_in[3];
    const float* ptw = (const float*)d_in[4];
    const float* ptb = (const float*)d_in[5];
    const float* e1w = (const float*)d_in[6];
    const float* e1b = (const float*)d_in[7];
    const float* e2w = (const float*)d_in[8];
    const float* e2b = (const float*)d_in[9];

    float* ws = (float*)d_ws;
    // Workspace (float-unit offsets; V = VOL):
    //   sp/tp fp16 [0,64V)        dead after corr -> h1 (fp32) reuses [0,128V)
    //   featT bf16 [128V,304V)    dead after conv1 -> h2 reuses [128V,256V)
    //   h1T bf16 [304V,368V)
    //   w1T bf16 [368V..), w2T, stats, pstats, zpad
    _Float16* sp  = (_Float16*)ws;
    _Float16* tp  = (_Float16*)(ws + (size_t)32 * VOL);
    ushort* featT = (ushort*)(ws + (size_t)128 * VOL);
    float*  h1    = ws;
    float*  h2    = ws + (size_t)128 * VOL;
    ushort* h1T   = (ushort*)(ws + (size_t)304 * VOL);
    float*  w1Tf  = ws + (size_t)368 * VOL;
    ushort* w1T   = (ushort*)w1Tf;
    float*  w2Tf  = w1Tf + 608256;           // 27*128*352 ushorts
    ushort* w2T   = (ushort*)w2Tf;
    float*  stats = w2Tf + 221184;           // 27*128*128 ushorts
    float*  pstats = stats + 256;            // 128*8*2 floats
    float*  zpadf  = pstats + 2048;          // 16B zero pad for conv staging
    const ushort* zpad = (const ushort*)zpadf;

    wprep_kernel<346, 352><<<128, 256, 0, stream>>>(e1w, w1T, zpadf);
    wprep_kernel<128, 128><<<128, 256, 0, stream>>>(e2w, w2T, zpadf);

    proj_l2norm_kernel<<<432, 256, 0, stream>>>(src, psw, psb, sp);
    proj_l2norm_kernel<<<432, 256, 0, stream>>>(tgt, ptw, ptb, tp);
    corr_fused_kernel<<<3456, 256, 0, stream>>>(sp, tp, featT);

    conv3_mfma_kernel<352><<<864, 256, 0, stream>>>(featT, w1T, e1b, zpad, h1);
    chan_stats_part_kernel<<<dim3(128, 8), 256, 0, stream>>>(h1, pstats);
    chan_stats_fin_kernel<<<1, 128, 0, stream>>>(pstats, stats);
    norm_gelu_transpose_kernel<<<dim3(3456, 4), 256, 0, stream>>>(h1, stats, h1T);

    conv3_mfma_kernel<128><<<864, 256, 0, stream>>>(h1T, w2T, e2b, zpad, h2);
    chan_stats_part_kernel<<<dim3(128, 8), 256, 0, stream>>>(h2, pstats);
    chan_stats_fin_kernel<<<1, 128, 0, stream>>>(pstats, stats);
    norm_gelu_kernel<<<(128 * VOL) / 1024, 256, 0, stream>>>(h2, stats, (float*)d_out);
}